// Round 12
// baseline (3921.429 us; speedup 1.0000x reference)
//
#include <hip/hip_runtime.h>
#include <math.h>

typedef _Float16 f16x8 __attribute__((ext_vector_type(8)));
typedef float f32x4 __attribute__((ext_vector_type(4)));
typedef unsigned long long u64;

// ---------------- output layout (floats) ----------------
#define OUT_PARAMS 0L
#define OUT_SCORE  1179648L
#define OUT_ROIS   1769472L
#define OUT_IDX    1779072L
#define OUT_ANCH   1781472L

// ---------------- workspace layout (float offsets) ----------------
#define WS_WT2   0L          // 512*54 f32
#define WS_W2H   27648L      // 9*512*512 f16 hi [tap][oc][c] (x1024)
#define WS_W2L   1207296L    // 9*512*512 f16 lo
#define WS_X2    2386944L    // 8*66*66*1024 f16: [n][row][col][cb16][hi32|lo32] (x512)
#define WS_MID   20229120L   // 8*512*4096 f32  (end 37,006,336 f32 = 148 MB)
// ---- overlay on X2 region (dead after conv) ----
#define WS_KEYS  2681856L    // 8*36864 u32
#define WS_BOX   2976768L    // 8*36864*4 f32
#define WS_SELK  4156416L    // 8*2048 u32
#define WS_SBOX  4172800L    // 8*2048*4 f32
#define WS_SUPP  4238336L    // 8*2000*32 u64  (end 5,262,336 < 20,229,120 OK)

// =============== K1: weight transform (split f16 hi/lo, x1024) ===============
__global__ void k_transpose_w(const float* __restrict__ conv_w,
                              const float* __restrict__ score_w,
                              const float* __restrict__ params_w,
                              _Float16* __restrict__ W2h, _Float16* __restrict__ W2l,
                              float* __restrict__ wt2) {
  int e = blockIdx.x * 256 + threadIdx.x;
  if (e < 9 * 512 * 512) {
    int tap = e >> 18, rem = e & 262143;
    int oc = rem >> 9, c = rem & 511;
    float v = conv_w[(oc * 512 + c) * 9 + tap] * 1024.0f;
    _Float16 h = (_Float16)v;
    W2h[e] = h;
    W2l[e] = (_Float16)(v - (float)h);
  }
  if (e < 512 * 54) {
    int o = e % 54, c = e / 54;
    wt2[e] = (o < 18) ? score_w[o * 512 + c] : params_w[(o - 18) * 512 + c];
  }
}

// =============== K2a: zero the pad borders of X2 ===============
__global__ void k_zero_pad(_Float16* __restrict__ X2) {
  const int t = blockIdx.x * 256 + threadIdx.x;
  if (t >= 8 * 260 * 128) return;
  const int s8 = t & 127;
  const int px_i = (t >> 7) % 260;
  const int n = (t >> 7) / 260;
  int prow, pcol;
  if (px_i < 66) { prow = 0; pcol = px_i; }
  else if (px_i < 132) { prow = 65; pcol = px_i - 66; }
  else if (px_i < 196) { prow = px_i - 132 + 1; pcol = 0; }
  else { prow = px_i - 196 + 1; pcol = 65; }
  _Float16* dst = X2 + (((size_t)(n * 66 + prow) * 66) + pcol) * 1024 + s8 * 8;
  float4 z = {0.f, 0.f, 0.f, 0.f};
  *(float4*)dst = z;
}

// =============== K2b: x NCHW f32 -> X2 interleaved f16 hi/lo (x512) ===============
__global__ __launch_bounds__(256) void k_split_x(const float* __restrict__ x,
                                                 _Float16* __restrict__ X2) {
  __shared__ float t[64][67];
  const int pxb = blockIdx.x;   // image row 0..63
  const int c0  = blockIdx.y * 64;
  const int n   = blockIdx.z;
  const int tid = threadIdx.x;
  const int a = tid >> 6, b = tid & 63;
#pragma unroll
  for (int i = 0; i < 16; ++i) {
    int c_l = i * 4 + a;
    t[c_l][b] = x[((size_t)(n * 512 + c0 + c_l) * 4096) + pxb * 64 + b];
  }
  __syncthreads();
#pragma unroll
  for (int it = 0; it < 2; ++it) {
    const int w = it * 256 + tid;       // 0..511
    const int px_l = w >> 3, cg8 = w & 7;
    f16x8 hv, lv;
#pragma unroll
    for (int j = 0; j < 8; ++j) {
      const float fs = t[cg8 * 8 + j][px_l] * 512.0f;
      const _Float16 h = (_Float16)fs;
      hv[j] = h;
      lv[j] = (_Float16)(fs - (float)h);
    }
    const int c = c0 + cg8 * 8;
    const int cb = c >> 5, cloc = c & 31;
    _Float16* base = X2 + (((size_t)(n * 66 + pxb + 1) * 66) + px_l + 1) * 1024 + cb * 64;
    *(f16x8*)(base + cloc) = hv;
    *(f16x8*)(base + 32 + cloc) = lv;
  }
}

// =============== K3: 3x3 conv, f16x3 split MFMA (r9 structure, 4 blocks/CU) ===============
// Fetch-stable synchronous 2-barrier staging, BK=32.
// Single change vs r11: __launch_bounds__(256, 4) -> 4 co-resident blocks/CU
// (LDS 4x33.8=135KB<160, VGPR cap 512/4=128 = current usage) so staggered
// blocks cover each other's staging/drain windows.
__global__ __launch_bounds__(256, 4) void k_conv_mfma(
    const _Float16* __restrict__ X2,
    const _Float16* __restrict__ W2h, const _Float16* __restrict__ W2l,
    const float* __restrict__ bias, float* __restrict__ mid) {
  __shared__ _Float16 XH[8448];   // [264 px][32 c], 16B-slot swizzled
  __shared__ _Float16 XL[8448];

  const int n   = blockIdx.x >> 5;
  const int rp  = blockIdx.x & 31;
  const int oc0 = blockIdx.y * 128;
  const int tid = threadIdx.x;
  const int lane = tid & 63, wid = tid >> 6;
  const int wm = wid >> 1, wn = wid & 1;
  const int l15 = lane & 15, kg = lane >> 4;

  f32x4 acch[4][4], accl[4][4];
#pragma unroll
  for (int i = 0; i < 4; ++i)
#pragma unroll
    for (int j = 0; j < 4; ++j) {
      acch[i][j] = (f32x4){0.f, 0.f, 0.f, 0.f};
      accl[i][j] = (f32x4){0.f, 0.f, 0.f, 0.f};
    }

  for (int cb = 0; cb < 16; ++cb) {
    __syncthreads();
    // ---- stage X tile: 264 px x 32c hi + lo, pure copy from X2 ----
    for (int u = tid; u < 1056; u += 256) {
      const int px = u >> 2, sd = u & 3;
      const int cg = sd ^ ((px >> 1) & 3);    // source channel-group for slot
      const int hrow = px / 66, hcol = px - hrow * 66;
      const _Float16* base = X2 +
          (((size_t)(n * 66 + rp * 2 + hrow) * 66) + hcol) * 1024 + cb * 64;
      const f16x8 hv = *(const f16x8*)(base + cg * 8);
      const f16x8 lv = *(const f16x8*)(base + 32 + cg * 8);
      *(f16x8*)(XH + u * 8) = hv;
      *(f16x8*)(XL + u * 8) = lv;
    }
    __syncthreads();

    // ---- compute 9 taps ----
#pragma unroll
    for (int ky = 0; ky < 3; ++ky) {
#pragma unroll
      for (int kx = 0; kx < 3; ++kx) {
        const int tap = ky * 3 + kx;
        f16x8 ah[4], al[4], bh[4], bl[4];
#pragma unroll
        for (int mf = 0; mf < 4; ++mf) {
          const size_t aoff =
              ((size_t)(tap * 512 + oc0 + wm * 64 + mf * 16 + l15)) * 512 + cb * 32 + kg * 8;
          ah[mf] = *(const f16x8*)(W2h + aoff);
          al[mf] = *(const f16x8*)(W2l + aoff);
        }
#pragma unroll
        for (int nf = 0; nf < 4; ++nf) {
          const int lpx = (wn + ky) * 66 + nf * 16 + l15 + kx;
          const int off = lpx * 32 + ((kg ^ ((lpx >> 1) & 3)) * 8);
          bh[nf] = *(const f16x8*)(&XH[off]);
          bl[nf] = *(const f16x8*)(&XL[off]);
        }
#pragma unroll
        for (int mf = 0; mf < 4; ++mf)
#pragma unroll
          for (int nf = 0; nf < 4; ++nf) {
            acch[mf][nf] = __builtin_amdgcn_mfma_f32_16x16x32_f16(ah[mf], bh[nf], acch[mf][nf], 0, 0, 0);
            accl[mf][nf] = __builtin_amdgcn_mfma_f32_16x16x32_f16(ah[mf], bl[nf], accl[mf][nf], 0, 0, 0);
            accl[mf][nf] = __builtin_amdgcn_mfma_f32_16x16x32_f16(al[mf], bh[nf], accl[mf][nf], 0, 0, 0);
          }
      }
    }
  }

  // epilogue: combine, unscale, bias, relu, store NCHW
  const float inv = 1.0f / (1024.0f * 512.0f);
  const int y = rp * 2 + wn;
#pragma unroll
  for (int mf = 0; mf < 4; ++mf) {
#pragma unroll
    for (int r = 0; r < 4; ++r) {
      const int oc = oc0 + wm * 64 + mf * 16 + kg * 4 + r;
      const float bv = bias[oc];
      float* mp = mid + (((size_t)(n * 512 + oc) * 64 + y) * 64);
#pragma unroll
      for (int nf = 0; nf < 4; ++nf) {
        const int xcol = nf * 16 + l15;
        mp[xcol] = fmaxf((acch[mf][nf][r] + accl[mf][nf][r]) * inv + bv, 0.f);
      }
    }
  }
}

// =============== K4: 1x1 convs + softmax + proposals (fused) ===============
__global__ __launch_bounds__(256) void k_1x1(
    const float* __restrict__ mid, const float* __restrict__ wt2,
    const float* __restrict__ score_b, const float* __restrict__ params_b,
    const int* __restrict__ ih_p, const int* __restrict__ iw_p,
    float* __restrict__ out, float* __restrict__ boxes,
    unsigned int* __restrict__ keys) {
  const int t = blockIdx.x * 256 + threadIdx.x;   // 0..65535
  const int half = t & 1;
  const int p = t >> 1;                           // px 0..32767
  const int n = p >> 12, hw = p & 4095;
  float acc[54];
#pragma unroll
  for (int o = 0; o < 54; ++o) acc[o] = 0.f;
  const float* m = mid + (size_t)n * 2097152 + (size_t)half * 256 * 4096 + hw;
  const float* wt = wt2 + half * 256 * 54;
  for (int c = 0; c < 256; ++c) {
    const float mv = m[(size_t)c * 4096];
    const float* w = wt + c * 54;
#pragma unroll
    for (int o = 0; o < 54; ++o) acc[o] = fmaf(w[o], mv, acc[o]);
  }
#pragma unroll
  for (int o = 0; o < 54; ++o) acc[o] += __shfl_xor(acc[o], 1);
  if (half) return;
#pragma unroll
  for (int o = 0; o < 18; ++o) acc[o] += score_b[o];
#pragma unroll
  for (int o = 0; o < 36; ++o) acc[18 + o] += params_b[o];

  float* so = out + OUT_SCORE + (size_t)n * 73728 + (size_t)hw * 18;
#pragma unroll
  for (int o = 0; o < 18; ++o) so[o] = acc[o];
  float* po = out + OUT_PARAMS + (size_t)n * 147456 + (size_t)hw * 36;
#pragma unroll
  for (int o = 0; o < 36; ++o) po[o] = acc[18 + o];

  // ---- fused proposals: 9 anchors of this px ----
  const float ih = (float)ih_p[0], iw = (float)iw_p[0];
  const float ratios[3] = {0.5f, 1.f, 2.f};
  const float scales[3] = {8.f, 16.f, 32.f};
  const float sy = (float)((hw >> 6) * 16);
  const float sx = (float)((hw & 63) * 16);
#pragma unroll
  for (int a = 0; a < 9; ++a) {
    const float rr = ratios[a / 3], sc = scales[a % 3];
    const float hs = (16.f * sc) * sqrtf(rr);
    const float ws_ = (16.f * sc) * sqrtf(1.f / rr);
    const float ay1 = sy + (8.f - hs * 0.5f), ax1 = sx + (8.f - ws_ * 0.5f);
    const float ay2 = sy + (8.f + hs * 0.5f), ax2 = sx + (8.f + ws_ * 0.5f);
    const int i = hw * 9 + a;
    if (n == 0) {
      float4 av; av.x = ay1; av.y = ax1; av.z = ay2; av.w = ax2;
      *(float4*)&out[OUT_ANCH + (size_t)i * 4] = av;
    }
    const float ah = ay2 - ay1, aw = ax2 - ax1;
    const float acy = ay1 + 0.5f * ah, acx = ax1 + 0.5f * aw;
    const float dy = acc[18 + a * 4 + 0], dx = acc[18 + a * 4 + 1];
    const float dh = acc[18 + a * 4 + 2], dw = acc[18 + a * 4 + 3];
    const float cy = dy * ah + acy, cx = dx * aw + acx;
    const float h = expf(dh) * ah, w = expf(dw) * aw;
    const float y1 = fminf(fmaxf(cy - 0.5f * h, 0.f), ih);
    const float x1 = fminf(fmaxf(cx - 0.5f * w, 0.f), iw);
    const float y2 = fminf(fmaxf(cy + 0.5f * h, 0.f), ih);
    const float x2 = fminf(fmaxf(cx + 0.5f * w, 0.f), iw);
    const int g = n * 36864 + i;
    float4 bx; bx.x = y1; bx.y = x1; bx.z = y2; bx.w = x2;
    *(float4*)&boxes[(size_t)g * 4] = bx;
    const float d = acc[a * 2 + 1] - acc[a * 2 + 0];
    float s = 1.f / (1.f + expf(-d));
    if (!((y2 - y1) >= 16.f && (x2 - x1) >= 16.f)) s = -INFINITY;
    const unsigned int b = __float_as_uint(s);
    keys[g] = (b & 0x80000000u) ? ~b : (b | 0x80000000u);
  }
}

// =============== K6: radix-select top-2000 + bitonic sort (1024 thr) ===============
__global__ __launch_bounds__(1024) void k_select(
    const unsigned int* __restrict__ keys, const float* __restrict__ boxes,
    unsigned int* __restrict__ selkey, float* __restrict__ sboxes) {
  __shared__ unsigned int hist[16][256];
  __shared__ unsigned long long sel[4096];
  __shared__ unsigned int s_prefix, s_remk, s_cnt;
  const int n = blockIdx.x, tid = threadIdx.x;
  const int lane = tid & 63;
  const unsigned int* kk = keys + (size_t)n * 36864;
  if (tid == 0) { s_prefix = 0; s_remk = 2000; s_cnt = 0; }
  const int hslot = tid >> 6;

  for (int byte = 3; byte >= 0; --byte) {
    for (int b2 = tid; b2 < 4096; b2 += 1024) ((unsigned int*)hist)[b2] = 0;
    __syncthreads();
    const unsigned pfx = s_prefix;
    const unsigned hmask = (byte == 3) ? 0u : (0xFFFFFFFFu << ((byte + 1) * 8));
    for (int i2 = tid; i2 < 36864; i2 += 1024) {
      const unsigned k = kk[i2];
      if ((k & hmask) == (pfx & hmask)) {
        const unsigned b8 = (k >> (byte * 8)) & 255u;
        unsigned long long peers = __ballot(1);
#pragma unroll
        for (int bit = 0; bit < 8; ++bit) {
          const unsigned long long bb = __ballot((b8 >> bit) & 1u);
          peers &= ((b8 >> bit) & 1u) ? bb : ~bb;
        }
        peers &= __ballot(1);
        if (lane == __builtin_ctzll(peers))
          atomicAdd(&hist[hslot][b8], (unsigned)__popcll(peers));
      }
    }
    __syncthreads();
    if (tid < 256) {
      unsigned s2 = 0;
#pragma unroll
      for (int j = 0; j < 16; ++j) s2 += hist[j][tid];
      hist[0][tid] = s2;
    }
    __syncthreads();
    if (tid == 0) {
      unsigned rem = s_remk;
      int b2 = 255;
      for (;; --b2) {
        const unsigned c2 = hist[0][b2];
        if (c2 >= rem) break;
        rem -= c2;
      }
      s_prefix = pfx | ((unsigned)b2 << (byte * 8));
      s_remk = rem;
    }
    __syncthreads();
  }
  const unsigned T = s_prefix;

  for (int i2 = tid; i2 < 36864; i2 += 1024) {
    const unsigned k = kk[i2];
    if (k >= T) {
      const unsigned long long m = __ballot(1);
      const int ldr = __builtin_ctzll(m);
      unsigned basep = 0;
      if (lane == ldr) basep = atomicAdd(&s_cnt, (unsigned)__popcll(m));
      basep = __shfl(basep, ldr);
      const unsigned p2 = basep + (unsigned)__popcll(m & ((1ull << lane) - 1ull));
      if (p2 < 4096)
        sel[p2] = ((unsigned long long)k << 32) | (unsigned)(~i2);
    }
  }
  __syncthreads();
  unsigned cnt = s_cnt; if (cnt > 4096) cnt = 4096;
  for (int i2 = (int)cnt + tid; i2 < 4096; i2 += 1024) sel[i2] = 0ull;

  for (int k2 = 2; k2 <= 4096; k2 <<= 1) {
    for (int j = k2 >> 1; j > 0; j >>= 1) {
      __syncthreads();
      for (int t = tid; t < 2048; t += 1024) {
        const int i1 = (t << 1) - (t & (j - 1));
        const int i2 = i1 + j;
        const unsigned long long va = sel[i1], vb = sel[i2];
        const bool sw = ((i1 & k2) == 0) ? (va < vb) : (va > vb);
        if (sw) { sel[i1] = vb; sel[i2] = va; }
      }
    }
  }
  __syncthreads();

  for (int s2 = tid; s2 < 2048; s2 += 1024) {
    const unsigned long long comp = sel[s2];
    unsigned key = (unsigned)(comp >> 32);
    unsigned idx = ~(unsigned)(comp & 0xFFFFFFFFu);
    float4 bx; bx.x = 0.f; bx.y = 0.f; bx.z = 0.f; bx.w = 0.f;
    if (comp != 0ull) bx = *(const float4*)&boxes[((size_t)n * 36864 + idx) * 4];
    else key = 0;
    selkey[n * 2048 + s2] = key;
    *(float4*)&sboxes[((size_t)n * 2048 + s2) * 4] = bx;
  }
}

// =============== K7: NMS suppression bit-matrix ===============
__global__ void k_nms_matrix(const float* __restrict__ sboxes,
                             unsigned long long* __restrict__ supp) {
  const int t = blockIdx.x * 256 + threadIdx.x;
  if (t >= 8 * 2000 * 32) return;
  const int n = t / 64000, rem = t % 64000;
  const int i = rem >> 5, w = rem & 31;
  const float4 bi = *(const float4*)&sboxes[((size_t)n * 2048 + i) * 4];
  const float areai = (bi.z - bi.x) * (bi.w - bi.y);
  unsigned long long bits = 0ull;
  const int j0 = w * 64;
  for (int jj = 0; jj < 64; ++jj) {
    const int j = j0 + jj;
    if (j >= 2000) break;
    const float4 bj = *(const float4*)&sboxes[((size_t)n * 2048 + j) * 4];
    const float areaj = (bj.z - bj.x) * (bj.w - bj.y);
    const float yy1 = fmaxf(bi.x, bj.x), xx1 = fmaxf(bi.y, bj.y);
    const float yy2 = fminf(bi.z, bj.z), xx2 = fminf(bi.w, bj.w);
    const float ih2 = fmaxf(yy2 - yy1, 0.f), iw2 = fmaxf(xx2 - xx1, 0.f);
    const float inter = ih2 * iw2;
    const float iou = inter / (areai + areaj - inter + 1e-9f);
    if (iou > 0.7f) bits |= (1ull << jj);
  }
  supp[((size_t)n * 2000 + i) * 32 + w] = bits;
}

// =============== K8: serial greedy scan, 8-deep prefetch ===============
__global__ void k_nms_scan(const unsigned long long* __restrict__ supp,
                           const unsigned int* __restrict__ selkey,
                           const float* __restrict__ sboxes,
                           float* __restrict__ out) {
  const int n = blockIdx.x;
  const int lane = threadIdx.x;   // 64 threads = 1 wave
  const unsigned long long* sp = supp + (size_t)n * 64000;
  const bool ld = lane < 32;
  unsigned long long removed = 0ull, keepmask = 0ull;
#define LDROW(i) (ld ? sp[(size_t)(i) * 32 + lane] : 0ull)
  unsigned long long r0 = LDROW(0), r1 = LDROW(1), r2 = LDROW(2), r3 = LDROW(3),
                     r4 = LDROW(4), r5 = LDROW(5), r6 = LDROW(6), r7 = LDROW(7);
  for (int g = 0; g < 250; ++g) {
    unsigned long long n0 = 0, n1 = 0, n2 = 0, n3 = 0, n4 = 0, n5 = 0, n6 = 0, n7 = 0;
    if (g < 249) {
      const int nb = (g + 1) * 8;
      n0 = LDROW(nb); n1 = LDROW(nb + 1); n2 = LDROW(nb + 2); n3 = LDROW(nb + 3);
      n4 = LDROW(nb + 4); n5 = LDROW(nb + 5); n6 = LDROW(nb + 6); n7 = LDROW(nb + 7);
    }
#define STEP(K, RK)                                                       \
    {                                                                     \
      const int i = g * 8 + K;                                            \
      const unsigned long long remw = __shfl(removed, i >> 6);            \
      if (!((remw >> (i & 63)) & 1ull)) {                                 \
        if (ld) removed |= RK;                                            \
        if (lane == (i >> 6)) keepmask |= (1ull << (i & 63));             \
      }                                                                   \
    }
    STEP(0, r0) STEP(1, r1) STEP(2, r2) STEP(3, r3)
    STEP(4, r4) STEP(5, r5) STEP(6, r6) STEP(7, r7)
#undef STEP
    r0 = n0; r1 = n1; r2 = n2; r3 = n3; r4 = n4; r5 = n5; r6 = n6; r7 = n7;
  }
#undef LDROW
  int running = 0;
  for (int ci = 0; ci < 32; ++ci) {
    const unsigned long long km = __shfl(keepmask, ci);
    const int i = ci * 64 + lane;
    const unsigned key = selkey[n * 2048 + i];
    const bool fin = (key >= 0x80000000u);
    const bool kf = (((km >> lane) & 1ull) != 0ull) && fin;
    const unsigned long long ball = __ballot(kf);
    const int rank = running + __popcll(ball & ((1ull << lane) - 1ull));
    if (kf && rank < 300) {
      const float4 bx = *(const float4*)&sboxes[((size_t)n * 2048 + i) * 4];
      *(float4*)&out[OUT_ROIS + ((size_t)n * 300 + rank) * 4] = bx;
    }
    running += __popcll(ball);
  }
  const int kept = running < 300 ? running : 300;
  for (int r2 = kept + lane; r2 < 300; r2 += 64) {
    float4 z; z.x = 0.f; z.y = 0.f; z.z = 0.f; z.w = 0.f;
    *(float4*)&out[OUT_ROIS + ((size_t)n * 300 + r2) * 4] = z;
  }
  for (int r2 = lane; r2 < 300; r2 += 64)
    out[OUT_IDX + n * 300 + r2] = (float)n;
}

// =============== host ===============
extern "C" void kernel_launch(void* const* d_in, const int* in_sizes, int n_in,
                              void* d_out, int out_size, void* d_ws, size_t ws_size,
                              hipStream_t stream) {
  const float* x        = (const float*)d_in[0];
  const float* conv_w   = (const float*)d_in[1];
  const float* conv_b   = (const float*)d_in[2];
  const float* score_w  = (const float*)d_in[3];
  const float* score_b  = (const float*)d_in[4];
  const float* params_w = (const float*)d_in[5];
  const float* params_b = (const float*)d_in[6];
  const int*   ih       = (const int*)d_in[7];
  const int*   iw       = (const int*)d_in[8];
  float* out = (float*)d_out;
  float* ws  = (float*)d_ws;

  float* wt2 = ws + WS_WT2;
  _Float16* W2h = (_Float16*)(ws + WS_W2H);
  _Float16* W2l = (_Float16*)(ws + WS_W2L);
  _Float16* X2  = (_Float16*)(ws + WS_X2);
  float* mid = ws + WS_MID;
  unsigned int* keys = (unsigned int*)(ws + WS_KEYS);
  float* boxes = ws + WS_BOX;
  unsigned int* selkey = (unsigned int*)(ws + WS_SELK);
  float* sboxes = ws + WS_SBOX;
  u64* supp = (u64*)(ws + WS_SUPP);

  hipLaunchKernelGGL(k_transpose_w, dim3(9216), dim3(256), 0, stream,
                     conv_w, score_w, params_w, W2h, W2l, wt2);
  hipLaunchKernelGGL(k_zero_pad, dim3(1040), dim3(256), 0, stream, X2);
  hipLaunchKernelGGL(k_split_x, dim3(64, 8, 8), dim3(256), 0, stream, x, X2);
  hipLaunchKernelGGL(k_conv_mfma, dim3(256, 4), dim3(256), 0, stream,
                     X2, W2h, W2l, conv_b, mid);
  hipLaunchKernelGGL(k_1x1, dim3(256), dim3(256), 0, stream,
                     mid, wt2, score_b, params_b, ih, iw, out, boxes, keys);
  hipLaunchKernelGGL(k_select, dim3(8), dim3(1024), 0, stream,
                     keys, boxes, selkey, sboxes);
  hipLaunchKernelGGL(k_nms_matrix, dim3(2000), dim3(256), 0, stream,
                     sboxes, supp);
  hipLaunchKernelGGL(k_nms_scan, dim3(8), dim3(64), 0, stream,
                     supp, selkey, sboxes, out);
}

// Round 13
// 1341.989 us; speedup vs baseline: 2.9221x; 2.9221x over previous
//
#include <hip/hip_runtime.h>
#include <math.h>

typedef _Float16 f16x8 __attribute__((ext_vector_type(8)));
typedef float f32x4 __attribute__((ext_vector_type(4)));
typedef unsigned long long u64;

// ---------------- output layout (floats) ----------------
#define OUT_PARAMS 0L
#define OUT_SCORE  1179648L
#define OUT_ROIS   1769472L
#define OUT_IDX    1779072L
#define OUT_ANCH   1781472L

// ---------------- workspace layout (float offsets) ----------------
#define WS_WT2   0L          // 512*54 f32
#define WS_W2H   27648L      // 9*512*512 f16 hi [tap][oc][c] (x1024)
#define WS_W2L   1207296L    // 9*512*512 f16 lo
#define WS_X2    2386944L    // 8*66*66*1024 f16: [n][row][col][cb16][hi32|lo32] (x512)
#define WS_MID   20229120L   // 8*512*4096 f32  (end 37,006,336 f32 = 148 MB)
// ---- overlay on X2 region (dead after conv) ----
#define WS_FG    2386944L    // 8*36864 f32
#define WS_KEYS  2681856L    // 8*36864 u32
#define WS_BOX   2976768L    // 8*36864*4 f32
#define WS_SELK  4156416L    // 8*2048 u32
#define WS_SBOX  4172800L    // 8*2048*4 f32
#define WS_SUPP  4238336L    // 8*2000*32 u64  (end 5,262,336 < 20,229,120 OK)

// =============== K1: weight transform (split f16 hi/lo, x1024) ===============
__global__ void k_transpose_w(const float* __restrict__ conv_w,
                              const float* __restrict__ score_w,
                              const float* __restrict__ params_w,
                              _Float16* __restrict__ W2h, _Float16* __restrict__ W2l,
                              float* __restrict__ wt2) {
  int e = blockIdx.x * 256 + threadIdx.x;
  if (e < 9 * 512 * 512) {
    int tap = e >> 18, rem = e & 262143;
    int oc = rem >> 9, c = rem & 511;
    float v = conv_w[(oc * 512 + c) * 9 + tap] * 1024.0f;
    _Float16 h = (_Float16)v;
    W2h[e] = h;
    W2l[e] = (_Float16)(v - (float)h);
  }
  if (e < 512 * 54) {
    int o = e % 54, c = e / 54;
    wt2[e] = (o < 18) ? score_w[o * 512 + c] : params_w[(o - 18) * 512 + c];
  }
}

// =============== K2a: zero the pad borders of X2 ===============
__global__ void k_zero_pad(_Float16* __restrict__ X2) {
  const int t = blockIdx.x * 256 + threadIdx.x;
  if (t >= 8 * 260 * 128) return;
  const int s8 = t & 127;
  const int px_i = (t >> 7) % 260;
  const int n = (t >> 7) / 260;
  int prow, pcol;
  if (px_i < 66) { prow = 0; pcol = px_i; }
  else if (px_i < 132) { prow = 65; pcol = px_i - 66; }
  else if (px_i < 196) { prow = px_i - 132 + 1; pcol = 0; }
  else { prow = px_i - 196 + 1; pcol = 65; }
  _Float16* dst = X2 + (((size_t)(n * 66 + prow) * 66) + pcol) * 1024 + s8 * 8;
  float4 z = {0.f, 0.f, 0.f, 0.f};
  *(float4*)dst = z;
}

// =============== K2b: x NCHW f32 -> X2 interleaved f16 hi/lo (x512) ===============
__global__ __launch_bounds__(256) void k_split_x(const float* __restrict__ x,
                                                 _Float16* __restrict__ X2) {
  __shared__ float t[64][67];
  const int pxb = blockIdx.x;   // image row 0..63
  const int c0  = blockIdx.y * 64;
  const int n   = blockIdx.z;
  const int tid = threadIdx.x;
  const int a = tid >> 6, b = tid & 63;
#pragma unroll
  for (int i = 0; i < 16; ++i) {
    int c_l = i * 4 + a;
    t[c_l][b] = x[((size_t)(n * 512 + c0 + c_l) * 4096) + pxb * 64 + b];
  }
  __syncthreads();
#pragma unroll
  for (int it = 0; it < 2; ++it) {
    const int w = it * 256 + tid;       // 0..511
    const int px_l = w >> 3, cg8 = w & 7;
    f16x8 hv, lv;
#pragma unroll
    for (int j = 0; j < 8; ++j) {
      const float fs = t[cg8 * 8 + j][px_l] * 512.0f;
      const _Float16 h = (_Float16)fs;
      hv[j] = h;
      lv[j] = (_Float16)(fs - (float)h);
    }
    const int c = c0 + cg8 * 8;
    const int cb = c >> 5, cloc = c & 31;
    _Float16* base = X2 + (((size_t)(n * 66 + pxb + 1) * 66) + px_l + 1) * 1024 + cb * 64;
    *(f16x8*)(base + cloc) = hv;
    *(f16x8*)(base + 32 + cloc) = lv;
  }
}

// =============== K3: 3x3 conv, f16x3 split MFMA (converged r9 kernel) ===============
// Fetch-stable synchronous 2-barrier staging, BK=32, 2 blocks/CU.
// True reg footprint ~256 (128 VGPR + acc in unified file): do NOT raise
// occupancy (r12: (256,4) -> allocator spill, 8.9GB scratch). Do NOT use
// global_load_lds (r4-r8: 7-10x over-fetch). Do NOT issue loads in compute
// phase (r7: de-phased blocks, 3x fetch). This structure is converged.
__global__ __launch_bounds__(256, 2) void k_conv_mfma(
    const _Float16* __restrict__ X2,
    const _Float16* __restrict__ W2h, const _Float16* __restrict__ W2l,
    const float* __restrict__ bias, float* __restrict__ mid) {
  __shared__ _Float16 XH[8448];   // [264 px][32 c], 16B-slot swizzled
  __shared__ _Float16 XL[8448];

  const int n   = blockIdx.x >> 5;
  const int rp  = blockIdx.x & 31;
  const int oc0 = blockIdx.y * 128;
  const int tid = threadIdx.x;
  const int lane = tid & 63, wid = tid >> 6;
  const int wm = wid >> 1, wn = wid & 1;
  const int l15 = lane & 15, kg = lane >> 4;

  f32x4 acch[4][4], accl[4][4];
#pragma unroll
  for (int i = 0; i < 4; ++i)
#pragma unroll
    for (int j = 0; j < 4; ++j) {
      acch[i][j] = (f32x4){0.f, 0.f, 0.f, 0.f};
      accl[i][j] = (f32x4){0.f, 0.f, 0.f, 0.f};
    }

  for (int cb = 0; cb < 16; ++cb) {
    __syncthreads();
    // ---- stage X tile: 264 px x 32c hi + lo, pure copy from X2 ----
    for (int u = tid; u < 1056; u += 256) {
      const int px = u >> 2, sd = u & 3;
      const int cg = sd ^ ((px >> 1) & 3);    // source channel-group for slot
      const int hrow = px / 66, hcol = px - hrow * 66;
      const _Float16* base = X2 +
          (((size_t)(n * 66 + rp * 2 + hrow) * 66) + hcol) * 1024 + cb * 64;
      const f16x8 hv = *(const f16x8*)(base + cg * 8);
      const f16x8 lv = *(const f16x8*)(base + 32 + cg * 8);
      *(f16x8*)(XH + u * 8) = hv;
      *(f16x8*)(XL + u * 8) = lv;
    }
    __syncthreads();

    // ---- compute 9 taps ----
#pragma unroll
    for (int ky = 0; ky < 3; ++ky) {
#pragma unroll
      for (int kx = 0; kx < 3; ++kx) {
        const int tap = ky * 3 + kx;
        f16x8 ah[4], al[4], bh[4], bl[4];
#pragma unroll
        for (int mf = 0; mf < 4; ++mf) {
          const size_t aoff =
              ((size_t)(tap * 512 + oc0 + wm * 64 + mf * 16 + l15)) * 512 + cb * 32 + kg * 8;
          ah[mf] = *(const f16x8*)(W2h + aoff);
          al[mf] = *(const f16x8*)(W2l + aoff);
        }
#pragma unroll
        for (int nf = 0; nf < 4; ++nf) {
          const int lpx = (wn + ky) * 66 + nf * 16 + l15 + kx;
          const int off = lpx * 32 + ((kg ^ ((lpx >> 1) & 3)) * 8);
          bh[nf] = *(const f16x8*)(&XH[off]);
          bl[nf] = *(const f16x8*)(&XL[off]);
        }
#pragma unroll
        for (int mf = 0; mf < 4; ++mf)
#pragma unroll
          for (int nf = 0; nf < 4; ++nf) {
            acch[mf][nf] = __builtin_amdgcn_mfma_f32_16x16x32_f16(ah[mf], bh[nf], acch[mf][nf], 0, 0, 0);
            accl[mf][nf] = __builtin_amdgcn_mfma_f32_16x16x32_f16(ah[mf], bl[nf], accl[mf][nf], 0, 0, 0);
            accl[mf][nf] = __builtin_amdgcn_mfma_f32_16x16x32_f16(al[mf], bh[nf], accl[mf][nf], 0, 0, 0);
          }
      }
    }
  }

  // epilogue: combine, unscale, bias, relu, store NCHW
  const float inv = 1.0f / (1024.0f * 512.0f);
  const int y = rp * 2 + wn;
#pragma unroll
  for (int mf = 0; mf < 4; ++mf) {
#pragma unroll
    for (int r = 0; r < 4; ++r) {
      const int oc = oc0 + wm * 64 + mf * 16 + kg * 4 + r;
      const float bv = bias[oc];
      float* mp = mid + (((size_t)(n * 512 + oc) * 64 + y) * 64);
#pragma unroll
      for (int nf = 0; nf < 4; ++nf) {
        const int xcol = nf * 16 + l15;
        mp[xcol] = fmaxf((acch[mf][nf][r] + accl[mf][nf][r]) * inv + bv, 0.f);
      }
    }
  }
}

// =============== K4: 1x1 convs + softmax (2-way c-split, all SIMDs) ===============
__global__ __launch_bounds__(256) void k_1x1(
    const float* __restrict__ mid, const float* __restrict__ wt2,
    const float* __restrict__ score_b, const float* __restrict__ params_b,
    float* __restrict__ out, float* __restrict__ fg) {
  const int t = blockIdx.x * 256 + threadIdx.x;   // 0..65535
  const int half = t & 1;
  const int p = t >> 1;                           // px 0..32767
  const int n = p >> 12, hw = p & 4095;
  float acc[54];
#pragma unroll
  for (int o = 0; o < 54; ++o) acc[o] = 0.f;
  const float* m = mid + (size_t)n * 2097152 + (size_t)half * 256 * 4096 + hw;
  const float* wt = wt2 + half * 256 * 54;
  for (int c = 0; c < 256; ++c) {
    const float mv = m[(size_t)c * 4096];
    const float* w = wt + c * 54;
#pragma unroll
    for (int o = 0; o < 54; ++o) acc[o] = fmaf(w[o], mv, acc[o]);
  }
#pragma unroll
  for (int o = 0; o < 54; ++o) acc[o] += __shfl_xor(acc[o], 1);
  if (half) return;
#pragma unroll
  for (int o = 0; o < 18; ++o) acc[o] += score_b[o];
#pragma unroll
  for (int o = 0; o < 36; ++o) acc[18 + o] += params_b[o];

  float* so = out + OUT_SCORE + (size_t)n * 73728 + (size_t)hw * 18;
#pragma unroll
  for (int o = 0; o < 18; ++o) so[o] = acc[o];
  float* po = out + OUT_PARAMS + (size_t)n * 147456 + (size_t)hw * 36;
#pragma unroll
  for (int o = 0; o < 36; ++o) po[o] = acc[18 + o];
  float* f = fg + (size_t)n * 36864 + hw * 9;
#pragma unroll
  for (int a = 0; a < 9; ++a) {
    float d = acc[a * 2 + 1] - acc[a * 2 + 0];
    f[a] = 1.f / (1.f + expf(-d));
  }
}

// =============== K5: anchors, loc2bbox, clip, min-size, sort keys ===============
__global__ void k_proposals(const float* __restrict__ out_params,
                            const float* __restrict__ fg,
                            const int* __restrict__ ih_p, const int* __restrict__ iw_p,
                            float* __restrict__ boxes, unsigned int* __restrict__ keys,
                            float* __restrict__ anchor_out) {
  const int g = blockIdx.x * 256 + threadIdx.x;
  if (g >= 8 * 36864) return;
  const int n = g / 36864, i = g % 36864;
  const int hw = i / 9, a = i % 9;
  const float ih = (float)ih_p[0], iw = (float)iw_p[0];
  const float ratios[3] = {0.5f, 1.f, 2.f};
  const float scales[3] = {8.f, 16.f, 32.f};
  const float rr = ratios[a / 3], sc = scales[a % 3];
  const float hs = (16.f * sc) * sqrtf(rr);
  const float ws_ = (16.f * sc) * sqrtf(1.f / rr);
  const float sy = (float)((hw >> 6) * 16);
  const float sx = (float)((hw & 63) * 16);
  const float ay1 = sy + (8.f - hs * 0.5f), ax1 = sx + (8.f - ws_ * 0.5f);
  const float ay2 = sy + (8.f + hs * 0.5f), ax2 = sx + (8.f + ws_ * 0.5f);
  if (n == 0) {
    float4 av; av.x = ay1; av.y = ax1; av.z = ay2; av.w = ax2;
    *(float4*)&anchor_out[(size_t)i * 4] = av;
  }
  const float ah = ay2 - ay1, aw = ax2 - ax1;
  const float acy = ay1 + 0.5f * ah, acx = ax1 + 0.5f * aw;
  const float* loc = out_params + (size_t)n * 147456 + (size_t)i * 4;
  const float dy = loc[0], dx = loc[1], dh = loc[2], dw = loc[3];
  const float cy = dy * ah + acy, cx = dx * aw + acx;
  const float h = expf(dh) * ah, w = expf(dw) * aw;
  const float y1 = fminf(fmaxf(cy - 0.5f * h, 0.f), ih);
  const float x1 = fminf(fmaxf(cx - 0.5f * w, 0.f), iw);
  const float y2 = fminf(fmaxf(cy + 0.5f * h, 0.f), ih);
  const float x2 = fminf(fmaxf(cx + 0.5f * w, 0.f), iw);
  float4 bx; bx.x = y1; bx.y = x1; bx.z = y2; bx.w = x2;
  *(float4*)&boxes[(size_t)g * 4] = bx;
  float s = fg[g];
  if (!((y2 - y1) >= 16.f && (x2 - x1) >= 16.f)) s = -INFINITY;
  const unsigned int b = __float_as_uint(s);
  keys[g] = (b & 0x80000000u) ? ~b : (b | 0x80000000u);
}

// =============== K6: radix-select top-2000 + bitonic sort (1024 thr) ===============
__global__ __launch_bounds__(1024) void k_select(
    const unsigned int* __restrict__ keys, const float* __restrict__ boxes,
    unsigned int* __restrict__ selkey, float* __restrict__ sboxes) {
  __shared__ unsigned int hist[16][256];
  __shared__ unsigned long long sel[4096];
  __shared__ unsigned int s_prefix, s_remk, s_cnt;
  const int n = blockIdx.x, tid = threadIdx.x;
  const int lane = tid & 63;
  const unsigned int* kk = keys + (size_t)n * 36864;
  if (tid == 0) { s_prefix = 0; s_remk = 2000; s_cnt = 0; }
  const int hslot = tid >> 6;

  for (int byte = 3; byte >= 0; --byte) {
    for (int b2 = tid; b2 < 4096; b2 += 1024) ((unsigned int*)hist)[b2] = 0;
    __syncthreads();
    const unsigned pfx = s_prefix;
    const unsigned hmask = (byte == 3) ? 0u : (0xFFFFFFFFu << ((byte + 1) * 8));
    for (int i2 = tid; i2 < 36864; i2 += 1024) {
      const unsigned k = kk[i2];
      if ((k & hmask) == (pfx & hmask)) {
        const unsigned b8 = (k >> (byte * 8)) & 255u;
        unsigned long long peers = __ballot(1);
#pragma unroll
        for (int bit = 0; bit < 8; ++bit) {
          const unsigned long long bb = __ballot((b8 >> bit) & 1u);
          peers &= ((b8 >> bit) & 1u) ? bb : ~bb;
        }
        peers &= __ballot(1);
        if (lane == __builtin_ctzll(peers))
          atomicAdd(&hist[hslot][b8], (unsigned)__popcll(peers));
      }
    }
    __syncthreads();
    if (tid < 256) {
      unsigned s2 = 0;
#pragma unroll
      for (int j = 0; j < 16; ++j) s2 += hist[j][tid];
      hist[0][tid] = s2;
    }
    __syncthreads();
    if (tid == 0) {
      unsigned rem = s_remk;
      int b2 = 255;
      for (;; --b2) {
        const unsigned c2 = hist[0][b2];
        if (c2 >= rem) break;
        rem -= c2;
      }
      s_prefix = pfx | ((unsigned)b2 << (byte * 8));
      s_remk = rem;
    }
    __syncthreads();
  }
  const unsigned T = s_prefix;

  for (int i2 = tid; i2 < 36864; i2 += 1024) {
    const unsigned k = kk[i2];
    if (k >= T) {
      const unsigned long long m = __ballot(1);
      const int ldr = __builtin_ctzll(m);
      unsigned basep = 0;
      if (lane == ldr) basep = atomicAdd(&s_cnt, (unsigned)__popcll(m));
      basep = __shfl(basep, ldr);
      const unsigned p2 = basep + (unsigned)__popcll(m & ((1ull << lane) - 1ull));
      if (p2 < 4096)
        sel[p2] = ((unsigned long long)k << 32) | (unsigned)(~i2);
    }
  }
  __syncthreads();
  unsigned cnt = s_cnt; if (cnt > 4096) cnt = 4096;
  for (int i2 = (int)cnt + tid; i2 < 4096; i2 += 1024) sel[i2] = 0ull;

  for (int k2 = 2; k2 <= 4096; k2 <<= 1) {
    for (int j = k2 >> 1; j > 0; j >>= 1) {
      __syncthreads();
      for (int t = tid; t < 2048; t += 1024) {
        const int i1 = (t << 1) - (t & (j - 1));
        const int i2 = i1 + j;
        const unsigned long long va = sel[i1], vb = sel[i2];
        const bool sw = ((i1 & k2) == 0) ? (va < vb) : (va > vb);
        if (sw) { sel[i1] = vb; sel[i2] = va; }
      }
    }
  }
  __syncthreads();

  for (int s2 = tid; s2 < 2048; s2 += 1024) {
    const unsigned long long comp = sel[s2];
    unsigned key = (unsigned)(comp >> 32);
    unsigned idx = ~(unsigned)(comp & 0xFFFFFFFFu);
    float4 bx; bx.x = 0.f; bx.y = 0.f; bx.z = 0.f; bx.w = 0.f;
    if (comp != 0ull) bx = *(const float4*)&boxes[((size_t)n * 36864 + idx) * 4];
    else key = 0;
    selkey[n * 2048 + s2] = key;
    *(float4*)&sboxes[((size_t)n * 2048 + s2) * 4] = bx;
  }
}

// =============== K7: NMS suppression bit-matrix (forward-only j>i) ===============
__global__ void k_nms_matrix(const float* __restrict__ sboxes,
                             unsigned long long* __restrict__ supp) {
  const int t = blockIdx.x * 256 + threadIdx.x;
  if (t >= 8 * 2000 * 32) return;
  const int n = t / 64000, rem = t % 64000;
  const int i = rem >> 5, w = rem & 31;
  u64* dst = &supp[((size_t)n * 2000 + i) * 32 + w];
  // only forward suppression (j > i) is consumed by the scan
  if (w < (i >> 6)) { *dst = 0ull; return; }
  const float4 bi = *(const float4*)&sboxes[((size_t)n * 2048 + i) * 4];
  const float areai = (bi.z - bi.x) * (bi.w - bi.y);
  unsigned long long bits = 0ull;
  const int j0 = w * 64;
  for (int jj = 0; jj < 64; ++jj) {
    const int j = j0 + jj;
    if (j >= 2000) break;
    const float4 bj = *(const float4*)&sboxes[((size_t)n * 2048 + j) * 4];
    const float areaj = (bj.z - bj.x) * (bj.w - bj.y);
    const float yy1 = fmaxf(bi.x, bj.x), xx1 = fmaxf(bi.y, bj.y);
    const float yy2 = fminf(bi.z, bj.z), xx2 = fminf(bi.w, bj.w);
    const float ih2 = fmaxf(yy2 - yy1, 0.f), iw2 = fmaxf(xx2 - xx1, 0.f);
    const float inter = ih2 * iw2;
    const float iou = inter / (areai + areaj - inter + 1e-9f);
    if (iou > 0.7f) bits |= (1ull << jj);
  }
  if (w == (i >> 6)) bits &= ~(((1ull << (i & 63)) << 1) - 1ull);  // keep only jj > i&63
  *dst = bits;
}

// =============== K8: serial greedy scan, 8-deep prefetch ===============
__global__ void k_nms_scan(const unsigned long long* __restrict__ supp,
                           const unsigned int* __restrict__ selkey,
                           const float* __restrict__ sboxes,
                           float* __restrict__ out) {
  const int n = blockIdx.x;
  const int lane = threadIdx.x;   // 64 threads = 1 wave
  const unsigned long long* sp = supp + (size_t)n * 64000;
  const bool ld = lane < 32;
  unsigned long long removed = 0ull, keepmask = 0ull;
#define LDROW(i) (ld ? sp[(size_t)(i) * 32 + lane] : 0ull)
  unsigned long long r0 = LDROW(0), r1 = LDROW(1), r2 = LDROW(2), r3 = LDROW(3),
                     r4 = LDROW(4), r5 = LDROW(5), r6 = LDROW(6), r7 = LDROW(7);
  for (int g = 0; g < 250; ++g) {
    unsigned long long n0 = 0, n1 = 0, n2 = 0, n3 = 0, n4 = 0, n5 = 0, n6 = 0, n7 = 0;
    if (g < 249) {
      const int nb = (g + 1) * 8;
      n0 = LDROW(nb); n1 = LDROW(nb + 1); n2 = LDROW(nb + 2); n3 = LDROW(nb + 3);
      n4 = LDROW(nb + 4); n5 = LDROW(nb + 5); n6 = LDROW(nb + 6); n7 = LDROW(nb + 7);
    }
#define STEP(K, RK)                                                       \
    {                                                                     \
      const int i = g * 8 + K;                                            \
      const unsigned long long remw = __shfl(removed, i >> 6);            \
      if (!((remw >> (i & 63)) & 1ull)) {                                 \
        if (ld) removed |= RK;                                            \
        if (lane == (i >> 6)) keepmask |= (1ull << (i & 63));             \
      }                                                                   \
    }
    STEP(0, r0) STEP(1, r1) STEP(2, r2) STEP(3, r3)
    STEP(4, r4) STEP(5, r5) STEP(6, r6) STEP(7, r7)
#undef STEP
    r0 = n0; r1 = n1; r2 = n2; r3 = n3; r4 = n4; r5 = n5; r6 = n6; r7 = n7;
  }
#undef LDROW
  int running = 0;
  for (int ci = 0; ci < 32; ++ci) {
    const unsigned long long km = __shfl(keepmask, ci);
    const int i = ci * 64 + lane;
    const unsigned key = selkey[n * 2048 + i];
    const bool fin = (key >= 0x80000000u);
    const bool kf = (((km >> lane) & 1ull) != 0ull) && fin;
    const unsigned long long ball = __ballot(kf);
    const int rank = running + __popcll(ball & ((1ull << lane) - 1ull));
    if (kf && rank < 300) {
      const float4 bx = *(const float4*)&sboxes[((size_t)n * 2048 + i) * 4];
      *(float4*)&out[OUT_ROIS + ((size_t)n * 300 + rank) * 4] = bx;
    }
    running += __popcll(ball);
  }
  const int kept = running < 300 ? running : 300;
  for (int r2 = kept + lane; r2 < 300; r2 += 64) {
    float4 z; z.x = 0.f; z.y = 0.f; z.z = 0.f; z.w = 0.f;
    *(float4*)&out[OUT_ROIS + ((size_t)n * 300 + r2) * 4] = z;
  }
  for (int r2 = lane; r2 < 300; r2 += 64)
    out[OUT_IDX + n * 300 + r2] = (float)n;
}

// =============== host ===============
extern "C" void kernel_launch(void* const* d_in, const int* in_sizes, int n_in,
                              void* d_out, int out_size, void* d_ws, size_t ws_size,
                              hipStream_t stream) {
  const float* x        = (const float*)d_in[0];
  const float* conv_w   = (const float*)d_in[1];
  const float* conv_b   = (const float*)d_in[2];
  const float* score_w  = (const float*)d_in[3];
  const float* score_b  = (const float*)d_in[4];
  const float* params_w = (const float*)d_in[5];
  const float* params_b = (const float*)d_in[6];
  const int*   ih       = (const int*)d_in[7];
  const int*   iw       = (const int*)d_in[8];
  float* out = (float*)d_out;
  float* ws  = (float*)d_ws;

  float* wt2 = ws + WS_WT2;
  _Float16* W2h = (_Float16*)(ws + WS_W2H);
  _Float16* W2l = (_Float16*)(ws + WS_W2L);
  _Float16* X2  = (_Float16*)(ws + WS_X2);
  float* mid = ws + WS_MID;
  float* fg  = ws + WS_FG;
  unsigned int* keys = (unsigned int*)(ws + WS_KEYS);
  float* boxes = ws + WS_BOX;
  unsigned int* selkey = (unsigned int*)(ws + WS_SELK);
  float* sboxes = ws + WS_SBOX;
  u64* supp = (u64*)(ws + WS_SUPP);

  hipLaunchKernelGGL(k_transpose_w, dim3(9216), dim3(256), 0, stream,
                     conv_w, score_w, params_w, W2h, W2l, wt2);
  hipLaunchKernelGGL(k_zero_pad, dim3(1040), dim3(256), 0, stream, X2);
  hipLaunchKernelGGL(k_split_x, dim3(64, 8, 8), dim3(256), 0, stream, x, X2);
  hipLaunchKernelGGL(k_conv_mfma, dim3(256, 4), dim3(256), 0, stream,
                     X2, W2h, W2l, conv_b, mid);
  hipLaunchKernelGGL(k_1x1, dim3(256), dim3(256), 0, stream,
                     mid, wt2, score_b, params_b, out, fg);
  hipLaunchKernelGGL(k_proposals, dim3(1152), dim3(256), 0, stream,
                     out + OUT_PARAMS, fg, ih, iw, boxes, keys, out + OUT_ANCH);
  hipLaunchKernelGGL(k_select, dim3(8), dim3(1024), 0, stream,
                     keys, boxes, selkey, sboxes);
  hipLaunchKernelGGL(k_nms_matrix, dim3(2000), dim3(256), 0, stream,
                     sboxes, supp);
  hipLaunchKernelGGL(k_nms_scan, dim3(8), dim3(64), 0, stream,
                     supp, selkey, sboxes, out);
}